// Round 1
// baseline (164.487 us; speedup 1.0000x reference)
//
#include <hip/hip_runtime.h>
#include <hip/hip_bf16.h>

#define BB 4
#define CCH 128
#define C2 256
#define OO 128
#define NVOX 32768            // 32*32*32 voxels per (b, channel)
#define NTOT (BB*NVOX)        // reduction count per output channel

typedef __attribute__((ext_vector_type(4))) float f32x4;
typedef __attribute__((ext_vector_type(8))) short s16x8;
typedef unsigned int u32;
typedef unsigned short u16;

__device__ __forceinline__ float bf2f(short s){
  union { u32 i; float f; } cv; cv.i = ((u32)(u16)s) << 16; return cv.f;
}
__device__ __forceinline__ short f2bf(float f){
  union { __hip_bfloat16 h; short s; } cv; cv.h = __float2bfloat16(f); return cv.s;
}

// ---- K0: conv_w fp32 -> bf16 -------------------------------------------------
__global__ __launch_bounds__(256) void k_convw(const float* __restrict__ w, short* __restrict__ wb){
  int i = blockIdx.x*256 + threadIdx.x;
  wb[i] = f2bf(w[i]);
}

// ---- K1: x_j = max(0, x - min over same-parity-excl-self along H,W,D) -------
// block = one (b,c,h) slab of 32x32 (w,d). minW/minD via LDS, minH via global
// (L2-resident: XCD swizzle keeps all 32 h of a (b,c) on one XCD).
__global__ __launch_bounds__(256) void k_xj(const float* __restrict__ x, short* __restrict__ xc){
  __shared__ float sx[1024];
  u32 id = blockIdx.x;
  u32 xcd = id & 7, slot = id >> 3;
  u32 bc = xcd*64u + (slot >> 5);     // 512 (b,c) slices, 64 per XCD
  u32 h  = slot & 31;
  u32 b = bc >> 7, c = bc & 127;
  const float* __restrict__ sl = x + (size_t)bc*NVOX + h*1024;
  int t = threadIdx.x;
  *(f32x4*)(sx + t*4) = *(const f32x4*)(sl + t*4);
  __syncthreads();
  float xv[4], m[4];
  #pragma unroll
  for(int j=0;j<4;j++){
    int v = t + 256*j;
    int w = v >> 5, d = v & 31;
    xv[j] = sx[v];
    float mm = 1e30f;
    #pragma unroll
    for(int i=1;i<16;i++) mm = fminf(mm, sx[(w<<5) | ((d + 2*i)&31)]);
    #pragma unroll
    for(int i=1;i<16;i++) mm = fminf(mm, sx[(((w + 2*i)&31)<<5) | d]);
    m[j] = mm;
  }
  const float* __restrict__ bch = x + (size_t)bc*NVOX;
  #pragma unroll
  for(int i=1;i<16;i++){
    const float* p = bch + ((h + 2*i)&31)*1024;
    #pragma unroll
    for(int j=0;j<4;j++) m[j] = fminf(m[j], p[t + 256*j]);
  }
  short* __restrict__ px = xc + ((size_t)(b*C2 + c))*NVOX + h*1024;
  short* __restrict__ pj = px + (size_t)CCH*NVOX;
  #pragma unroll
  for(int j=0;j<4;j++){
    int v = t + 256*j;
    px[v] = f2bf(xv[j]);
    pj[v] = f2bf(fmaxf(0.0f, xv[j] - m[j]));
  }
}

// ---- K2: y[b,o,v] = sum_c W[o,c]*xc[b,c,v], bf16 MFMA ------------------------
// block: O=128 x V=128, K=256 in two 128-chunks staged LDS-transposed.
__global__ __launch_bounds__(256) void k_gemm(const short* __restrict__ xc, const short* __restrict__ wb,
                                              short* __restrict__ y){
  __shared__ __align__(16) short ldsB[128*136];   // [v 128][c 128], stride 136 shorts = 272B
  u32 blk = blockIdx.x;
  u32 vblk = blk & 255, b = blk >> 8;
  u32 vbase = vblk * 128;
  const short* __restrict__ xb = xc + (size_t)b*C2*NVOX;
  int t = threadIdx.x;
  int wave = t >> 6, lane = t & 63;
  int wr = wave >> 1, wc = wave & 1;    // o-half, v-half
  int l15 = lane & 15, l4 = lane >> 4;
  f32x4 acc[4][4];
  #pragma unroll
  for(int mt=0;mt<4;mt++)
    #pragma unroll
    for(int nt=0;nt<4;nt++) acc[mt][nt] = (f32x4){0.f,0.f,0.f,0.f};

  int cc0 = t >> 5, vv = t & 31;
  #pragma unroll
  for(int kc=0;kc<2;kc++){
    __syncthreads();
    #pragma unroll
    for(int it=0;it<16;it++){
      int cc = cc0 + it*8;
      const short* src = xb + (size_t)(kc*128 + cc)*NVOX + vbase;
      #pragma unroll
      for(int j=0;j<4;j++){
        int v = vv + 32*j;
        ldsB[v*136 + cc] = src[v];
      }
    }
    __syncthreads();
    #pragma unroll
    for(int ks=0;ks<4;ks++){
      int kk = ks*32 + l4*8;            // same k-mapping f(lane,i) for A and B
      s16x8 bfrag[4], afrag[4];
      #pragma unroll
      for(int nt=0;nt<4;nt++){
        int vloc = wc*64 + nt*16 + l15;
        bfrag[nt] = *(const s16x8*)(&ldsB[vloc*136 + kk]);
      }
      #pragma unroll
      for(int mt=0;mt<4;mt++){
        int o = wr*64 + mt*16 + l15;
        afrag[mt] = *(const s16x8*)(wb + o*C2 + kc*128 + kk);
      }
      #pragma unroll
      for(int mt=0;mt<4;mt++)
        #pragma unroll
        for(int nt=0;nt<4;nt++)
          acc[mt][nt] = __builtin_amdgcn_mfma_f32_16x16x32_bf16(afrag[mt], bfrag[nt], acc[mt][nt], 0,0,0);
    }
  }
  // C/D: col = lane&15 (v), row = (lane>>4)*4 + r (o)   [m89-verified]
  short* __restrict__ yb = y + (size_t)b*OO*NVOX + vbase;
  #pragma unroll
  for(int mt=0;mt<4;mt++){
    #pragma unroll
    for(int nt=0;nt<4;nt++){
      int vcol = wc*64 + nt*16 + l15;
      #pragma unroll
      for(int r=0;r<4;r++){
        int o = wr*64 + mt*16 + l4*4 + r;
        yb[(size_t)o*NVOX + vcol] = f2bf(acc[mt][nt][r]);
      }
    }
  }
}

// ---- K3: per-o mean / rstd over (b,v) ---------------------------------------
__global__ __launch_bounds__(256) void k_stats(const short* __restrict__ y, float* __restrict__ stats){
  int o = blockIdx.x, t = threadIdx.x;
  float s = 0.f, ss = 0.f;
  for(int b=0;b<BB;b++){
    const short* p = y + ((size_t)b*OO + o)*NVOX;
    for(int v = t*8; v < NVOX; v += 2048){
      s16x8 u = *(const s16x8*)(p + v);
      #pragma unroll
      for(int e=0;e<8;e++){ float f = bf2f(u[e]); s += f; ss += f*f; }
    }
  }
  __shared__ float rs[256], rss[256];
  rs[t] = s; rss[t] = ss;
  __syncthreads();
  for(int k=128;k>0;k>>=1){
    if(t<k){ rs[t]+=rs[t+k]; rss[t]+=rss[t+k]; }
    __syncthreads();
  }
  if(t==0){
    float inv = 1.0f/(float)NTOT;
    float mean = rs[0]*inv;
    float var = rss[0]*inv - mean*mean;
    stats[2*o]   = mean;
    stats[2*o+1] = rsqrtf(var + 1e-5f);
  }
}

// ---- K4: BN scale-shift + exact-erf GELU ------------------------------------
__global__ __launch_bounds__(256) void k_bngelu(const short* __restrict__ y, const float* __restrict__ stats,
                                                const float* __restrict__ gamma, const float* __restrict__ beta,
                                                float* __restrict__ out){
  size_t base = ((size_t)blockIdx.x*256 + threadIdx.x)*8;
  int o = (int)((base >> 15) & 127);
  float mean = stats[2*o], rstd = stats[2*o+1];
  float g  = gamma[o]*rstd;
  float be = beta[o] - mean*g;
  s16x8 u = *(const s16x8*)(y + base);
  f32x4 r0, r1;
  #pragma unroll
  for(int e=0;e<8;e++){
    float yn = bf2f(u[e])*g + be;
    float ge = 0.5f*yn*(1.0f + erff(yn*0.70710678118654752f));
    if(e<4) r0[e] = ge; else r1[e-4] = ge;
  }
  *(f32x4*)(out + base)     = r0;
  *(f32x4*)(out + base + 4) = r1;
}

extern "C" void kernel_launch(void* const* d_in, const int* in_sizes, int n_in,
                              void* d_out, int out_size, void* d_ws, size_t ws_size,
                              hipStream_t stream) {
  (void)in_sizes; (void)n_in; (void)out_size; (void)ws_size;
  const float* x     = (const float*)d_in[0];
  const float* cw    = (const float*)d_in[1];
  // d_in[2] = conv_b: mathematically cancels in training-mode BatchNorm
  const float* gamma = (const float*)d_in[3];
  const float* beta  = (const float*)d_in[4];
  float* out = (float*)d_out;

  char* ws = (char*)d_ws;
  short* wb    = (short*)ws;                                   // 64 KB bf16 W
  short* y     = (short*)(ws + 65536);                         // 33.5 MB bf16 y
  float* stats = (float*)(ws + 65536 + (size_t)BB*OO*NVOX*2);  // 1 KB
  short* xcbuf = (short*)d_out;                                // 67 MB scratch: xc lives in d_out
                                                               // until k_bngelu overwrites it

  k_convw <<<dim3((OO*C2)/256),     dim3(256), 0, stream>>>(cw, wb);
  k_xj    <<<dim3(BB*CCH*32),      dim3(256), 0, stream>>>(x, xcbuf);
  k_gemm  <<<dim3(BB*(NVOX/128)),  dim3(256), 0, stream>>>(xcbuf, wb, y);
  k_stats <<<dim3(OO),             dim3(256), 0, stream>>>(y, stats);
  k_bngelu<<<dim3((NTOT*OO)/2048), dim3(256), 0, stream>>>(y, stats, gamma, beta, out);
}

// Round 2
// 123.254 us; speedup vs baseline: 1.3345x; 1.3345x over previous
//
#include <hip/hip_runtime.h>
#include <hip/hip_bf16.h>

#define BB 4
#define CCH 128
#define C2 256
#define OO 128
#define NVOX 32768            // 32*32*32 voxels per (b, channel)
#define NTOT (BB*NVOX)        // reduction count per output channel

typedef __attribute__((ext_vector_type(4))) float f32x4;
typedef __attribute__((ext_vector_type(8))) short s16x8;
typedef unsigned int u32;
typedef unsigned short u16;

// XOR swizzle on the 16B column-block index, keyed by row. Bijective per row.
#define SWZ(r) ((((r)>>3) ^ (r)) & 7)

__device__ __forceinline__ float bf2f(short s){
  union { u32 i; float f; } cv; cv.i = ((u32)(u16)s) << 16; return cv.f;
}
__device__ __forceinline__ short f2bf(float f){
  union { __hip_bfloat16 h; short s; } cv; cv.h = __float2bfloat16(f); return cv.s;
}

// ---- K0: conv_w fp32 -> bf16 -------------------------------------------------
__global__ __launch_bounds__(256) void k_convw(const float* __restrict__ w, short* __restrict__ wb){
  int i = blockIdx.x*256 + threadIdx.x;
  wb[i] = f2bf(w[i]);
}

// ---- K1: x_j = max(0, x - min over same-parity-excl-self along H,W,D) -------
// block = one (b,c,h) slab of 32x32 (w,d). minW/minD via LDS, minH via global
// (L2-resident: XCD swizzle keeps all 32 h of a (b,c) on one XCD).
__global__ __launch_bounds__(256) void k_xj(const float* __restrict__ x, short* __restrict__ xc){
  __shared__ float sx[1024];
  u32 id = blockIdx.x;
  u32 xcd = id & 7, slot = id >> 3;
  u32 bc = xcd*64u + (slot >> 5);     // 512 (b,c) slices, 64 per XCD
  u32 h  = slot & 31;
  u32 b = bc >> 7, c = bc & 127;
  const float* __restrict__ sl = x + (size_t)bc*NVOX + h*1024;
  int t = threadIdx.x;
  *(f32x4*)(sx + t*4) = *(const f32x4*)(sl + t*4);
  __syncthreads();
  float xv[4], m[4];
  #pragma unroll
  for(int j=0;j<4;j++){
    int v = t + 256*j;
    int w = v >> 5, d = v & 31;
    xv[j] = sx[v];
    float mm = 1e30f;
    #pragma unroll
    for(int i=1;i<16;i++) mm = fminf(mm, sx[(w<<5) | ((d + 2*i)&31)]);
    #pragma unroll
    for(int i=1;i<16;i++) mm = fminf(mm, sx[(((w + 2*i)&31)<<5) | d]);
    m[j] = mm;
  }
  const float* __restrict__ bch = x + (size_t)bc*NVOX;
  #pragma unroll
  for(int i=1;i<16;i++){
    const float* p = bch + ((h + 2*i)&31)*1024;
    #pragma unroll
    for(int j=0;j<4;j++) m[j] = fminf(m[j], p[t + 256*j]);
  }
  short* __restrict__ px = xc + ((size_t)(b*C2 + c))*NVOX + h*1024;
  short* __restrict__ pj = px + (size_t)CCH*NVOX;
  #pragma unroll
  for(int j=0;j<4;j++){
    int v = t + 256*j;
    px[v] = f2bf(xv[j]);
    pj[v] = f2bf(fmaxf(0.0f, xv[j] - m[j]));
  }
}

// ---- K2: y[b,o,v] = sum_c W[o,c]*xc[b,c,v], bf16 MFMA ------------------------
// Tile O=128 x V=128, K=256 in two 128-chunks. B staged via coalesced s16x8
// loads -> in-register c-pair transpose -> ds_write_b32 into swizzled [v][c]
// (32 KB). A-frags direct from global (W is L2-hot). Epilogue through LDS.
__global__ __launch_bounds__(256) void k_gemm(const short* __restrict__ xc, const short* __restrict__ wb,
                                              short* __restrict__ y){
  __shared__ __align__(16) char lds[32768];      // [v 128][c 128] bf16, swizzled blocks
  u32 blk = blockIdx.x;
  u32 vblk = blk & 255, b = blk >> 8;
  u32 vbase = vblk * 128;
  const short* __restrict__ xb = xc + (size_t)b*C2*NVOX + vbase;
  int t = threadIdx.x;
  int wave = t >> 6, lane = t & 63;
  int wr = wave >> 1, wc = wave & 1;    // o-half, v-half
  int l15 = lane & 15, l4 = lane >> 4;
  f32x4 acc[4][4];
  #pragma unroll
  for(int mt=0;mt<4;mt++)
    #pragma unroll
    for(int nt=0;nt<4;nt++) acc[mt][nt] = (f32x4){0.f,0.f,0.f,0.f};

  int v0  = (t & 15) * 8;     // 8 consecutive v this thread stages
  int cb2 = 2 * (t >> 4);     // even c base, +32*q

  #pragma unroll
  for(int kc=0;kc<2;kc++){
    // coalesced loads: two adjacent c-rows x 8 v each
    s16x8 ra[4], rb[4];
    #pragma unroll
    for(int q=0;q<4;q++){
      const short* src = xb + (size_t)(kc*128 + cb2 + 32*q)*NVOX + v0;
      ra[q] = *(const s16x8*)(src);
      rb[q] = *(const s16x8*)(src + NVOX);
    }
    __syncthreads();                       // previous chunk fully consumed
    #pragma unroll
    for(int q=0;q<4;q++){
      int c = cb2 + 32*q;
      #pragma unroll
      for(int e=0;e<8;e++){
        int v = v0 + e;
        u32 pr = ((u32)(u16)ra[q][e]) | (((u32)(u16)rb[q][e]) << 16);
        *(u32*)(lds + v*256 + ((((c>>3) ^ SWZ(v))<<4) | ((c&7)<<1))) = pr;
      }
    }
    __syncthreads();
    #pragma unroll
    for(int ks=0;ks<4;ks++){
      int kk = ks*32 + l4*8;               // same k-mapping f(lane,j) for A and B
      s16x8 afrag[4], bfrag[4];
      #pragma unroll
      for(int nt=0;nt<4;nt++){
        int vloc = wc*64 + nt*16 + l15;
        bfrag[nt] = *(const s16x8*)(lds + vloc*256 + (((kk>>3) ^ SWZ(vloc))<<4));
      }
      #pragma unroll
      for(int mt=0;mt<4;mt++){
        int o = wr*64 + mt*16 + l15;
        afrag[mt] = *(const s16x8*)(wb + o*C2 + kc*128 + kk);
      }
      #pragma unroll
      for(int mt=0;mt<4;mt++)
        #pragma unroll
        for(int nt=0;nt<4;nt++)
          acc[mt][nt] = __builtin_amdgcn_mfma_f32_16x16x32_bf16(afrag[mt], bfrag[nt], acc[mt][nt], 0,0,0);
    }
  }

  // Epilogue: acc -> LDS [o 128][v 128] bf16 (swizzled) -> coalesced stores.
  // C/D: col = lane&15 (v), row = (lane>>4)*4 + r (o)   [m89-verified]
  __syncthreads();
  #pragma unroll
  for(int mt=0;mt<4;mt++){
    #pragma unroll
    for(int nt=0;nt<4;nt++){
      int vcol = wc*64 + nt*16 + l15;
      #pragma unroll
      for(int r=0;r<4;r++){
        int o = wr*64 + mt*16 + l4*4 + r;
        *(short*)(lds + o*256 + ((((vcol>>3) ^ SWZ(o))<<4) | ((vcol&7)<<1))) = f2bf(acc[mt][nt][r]);
      }
    }
  }
  __syncthreads();
  short* __restrict__ yb = y + (size_t)b*OO*NVOX + vbase;
  #pragma unroll
  for(int q=0;q<8;q++){
    int p = t + q*256;
    int o = p >> 4, vs = (p & 15) * 8;
    s16x8 val = *(const s16x8*)(lds + o*256 + ((((vs>>3) ^ SWZ(o))<<4)));
    *(s16x8*)(yb + (size_t)o*NVOX + vs) = val;
  }
}

// ---- K3: per-o mean / rstd over (b,v) ---------------------------------------
__global__ __launch_bounds__(256) void k_stats(const short* __restrict__ y, float* __restrict__ stats){
  int o = blockIdx.x, t = threadIdx.x;
  float s = 0.f, ss = 0.f;
  for(int b=0;b<BB;b++){
    const short* p = y + ((size_t)b*OO + o)*NVOX;
    for(int v = t*8; v < NVOX; v += 2048){
      s16x8 u = *(const s16x8*)(p + v);
      #pragma unroll
      for(int e=0;e<8;e++){ float f = bf2f(u[e]); s += f; ss += f*f; }
    }
  }
  __shared__ float rs[256], rss[256];
  rs[t] = s; rss[t] = ss;
  __syncthreads();
  for(int k=128;k>0;k>>=1){
    if(t<k){ rs[t]+=rs[t+k]; rss[t]+=rss[t+k]; }
    __syncthreads();
  }
  if(t==0){
    float inv = 1.0f/(float)NTOT;
    float mean = rs[0]*inv;
    float var = rss[0]*inv - mean*mean;
    stats[2*o]   = mean;
    stats[2*o+1] = rsqrtf(var + 1e-5f);
  }
}

// ---- K4: BN scale-shift + exact-erf GELU ------------------------------------
__global__ __launch_bounds__(256) void k_bngelu(const short* __restrict__ y, const float* __restrict__ stats,
                                                const float* __restrict__ gamma, const float* __restrict__ beta,
                                                float* __restrict__ out){
  size_t base = ((size_t)blockIdx.x*256 + threadIdx.x)*8;
  int o = (int)((base >> 15) & 127);
  float mean = stats[2*o], rstd = stats[2*o+1];
  float g  = gamma[o]*rstd;
  float be = beta[o] - mean*g;
  s16x8 u = *(const s16x8*)(y + base);
  f32x4 r0, r1;
  #pragma unroll
  for(int e=0;e<8;e++){
    float yn = bf2f(u[e])*g + be;
    float ge = 0.5f*yn*(1.0f + erff(yn*0.70710678118654752f));
    if(e<4) r0[e] = ge; else r1[e-4] = ge;
  }
  *(f32x4*)(out + base)     = r0;
  *(f32x4*)(out + base + 4) = r1;
}

extern "C" void kernel_launch(void* const* d_in, const int* in_sizes, int n_in,
                              void* d_out, int out_size, void* d_ws, size_t ws_size,
                              hipStream_t stream) {
  (void)in_sizes; (void)n_in; (void)out_size; (void)ws_size;
  const float* x     = (const float*)d_in[0];
  const float* cw    = (const float*)d_in[1];
  // d_in[2] = conv_b: mathematically cancels in training-mode BatchNorm
  const float* gamma = (const float*)d_in[3];
  const float* beta  = (const float*)d_in[4];
  float* out = (float*)d_out;

  char* ws = (char*)d_ws;
  short* wb    = (short*)ws;                                   // 64 KB bf16 W
  short* y     = (short*)(ws + 65536);                         // 33.5 MB bf16 y
  float* stats = (float*)(ws + 65536 + (size_t)BB*OO*NVOX*2);  // 1 KB
  short* xcbuf = (short*)d_out;                                // 67 MB scratch: xc lives in d_out
                                                               // until k_bngelu overwrites it

  k_convw <<<dim3((OO*C2)/256),     dim3(256), 0, stream>>>(cw, wb);
  k_xj    <<<dim3(BB*CCH*32),      dim3(256), 0, stream>>>(x, xcbuf);
  k_gemm  <<<dim3(BB*(NVOX/128)),  dim3(256), 0, stream>>>(xcbuf, wb, y);
  k_stats <<<dim3(OO),             dim3(256), 0, stream>>>(y, stats);
  k_bngelu<<<dim3((NTOT*OO)/2048), dim3(256), 0, stream>>>(y, stats, gamma, beta, out);
}

// Round 3
// 100.426 us; speedup vs baseline: 1.6379x; 1.2273x over previous
//
#include <hip/hip_runtime.h>
#include <hip/hip_bf16.h>

#define BB 4
#define CCH 128
#define C2 256
#define OO 128
#define NVOX 32768            // 32*32*32 voxels per (b, channel)
#define NTOT (BB*NVOX)        // reduction count per output channel

typedef __attribute__((ext_vector_type(4))) float f32x4;
typedef __attribute__((ext_vector_type(8))) short s16x8;
typedef __attribute__((ext_vector_type(4))) unsigned int u32x4;
typedef unsigned int u32;
typedef unsigned short u16;

// XOR swizzle on the 16B column-block index, keyed by row. Bijective per row. (GEMM)
#define SWZ(r) ((((r)>>3) ^ (r)) & 7)

__device__ __forceinline__ float bf2f(short s){
  union { u32 i; float f; } cv; cv.i = ((u32)(u16)s) << 16; return cv.f;
}
__device__ __forceinline__ short f2bf(float f){
  union { __hip_bfloat16 h; short s; } cv; cv.h = __float2bfloat16(f); return cv.s;
}
__device__ __forceinline__ u32 pack2(float a, float b){
  return ((u32)(u16)f2bf(a)) | (((u32)(u16)f2bf(b)) << 16);
}
__device__ __forceinline__ float ulo(u32 r){
  union { u32 i; float f; } cv; cv.i = r << 16; return cv.f;
}
__device__ __forceinline__ float uhi(u32 r){
  union { u32 i; float f; } cv; cv.i = r & 0xffff0000u; return cv.f;
}

// ---- K0: conv_w fp32 -> bf16 -------------------------------------------------
__global__ __launch_bounds__(256) void k_convw(const float* __restrict__ w, short* __restrict__ wb){
  int i = blockIdx.x*256 + threadIdx.x;
  wb[i] = f2bf(w[i]);
}

// ---- K1: x_j = max(0, x - min over same-parity-excl-self along H,W,D) -------
// One block per (b,c): whole 32^3 volume in LDS (bf16, swizzled). Per-axis
// min-excl-self via (min1,min2) parity-line tables: me = (x==min1)?min2:min1
// (duplicate-inclusive min2 makes this exact). D-axis computed inline in regs.
// LDS = 64KB volume + 8KB tabW + 8KB tabH = 80KB -> 2 blocks/CU.

// byte offset of logical (h, w, byte-in-line) in swizzled volume
__device__ __forceinline__ int swz3(int h, int w, int bin){
  int s1 = ((w>>1) ^ h) & 3;           // permutes 16B granules inside the 64B line
  int s2 = ((w>>3) ^ (h>>2)) & 3;      // relocates lines among w&3 group
  return (h<<11) + ((w ^ s2)<<6) + ((bin & 15) | (((((bin>>4)) ^ s1) & 3) << 4));
}

__global__ __launch_bounds__(256) void k_xj(const float* __restrict__ x, short* __restrict__ xc){
  __shared__ __align__(16) u32 xs[16384];   // 64KB: bf16 pairs, swizzled
  __shared__ __align__(16) u32 tw[2048];    // [h][pw][d] {min1,min2} packed
  __shared__ __align__(16) u32 th[2048];    // [ph][w][d], granule ^ (w&7)
  int t = threadIdx.x;
  u32 bc = blockIdx.x;
  const float* __restrict__ src = x + (size_t)bc*NVOX;

  // P1: stage volume as bf16, swizzled, coalesced f32x4 loads
  #pragma unroll
  for(int j=0;j<32;j++){
    int e0 = (t + 256*j)*4;
    f32x4 v = *(const f32x4*)(src + e0);
    int h = e0>>10, w = (e0>>5)&31, bin = (e0&31)*2;
    u32* dst = (u32*)((char*)xs + swz3(h,w,bin));
    dst[0] = pack2(v[0], v[1]);
    dst[1] = pack2(v[2], v[3]);
  }
  __syncthreads();

  // P2: build W-table (threads 0-127) and H-table (threads 128-255).
  // task = (axis-line aa, d-granule dg of 8 d's)
  {
    int task = t & 127, dg = task & 3, aa = task >> 2;
    float m1[2][8], m2[2][8];
    #pragma unroll
    for(int p=0;p<2;p++)
      #pragma unroll
      for(int k=0;k<8;k++){ m1[p][k]=1e30f; m2[p][k]=1e30f; }
    if(t < 128){
      int h = aa;
      #pragma unroll
      for(int w=0;w<32;w++){
        int p = w & 1;
        u32x4 g = *(const u32x4*)((const char*)xs + swz3(h,w,dg<<4));
        #pragma unroll
        for(int q=0;q<4;q++){
          float a = ulo(g[q]), b = uhi(g[q]);
          m2[p][2*q]   = fminf(m2[p][2*q],   fmaxf(m1[p][2*q],   a)); m1[p][2*q]   = fminf(m1[p][2*q],   a);
          m2[p][2*q+1] = fminf(m2[p][2*q+1], fmaxf(m1[p][2*q+1], b)); m1[p][2*q+1] = fminf(m1[p][2*q+1], b);
        }
      }
      #pragma unroll
      for(int p=0;p<2;p++){
        u32 o[8];
        #pragma unroll
        for(int k=0;k<8;k++) o[k] = pack2(m1[p][k], m2[p][k]);
        u32* d0 = &tw[h*64 + p*32 + dg*8];
        *(u32x4*)d0     = (u32x4){o[0],o[1],o[2],o[3]};
        *(u32x4*)(d0+4) = (u32x4){o[4],o[5],o[6],o[7]};
      }
    } else {
      int w = aa;
      #pragma unroll
      for(int h=0;h<32;h++){
        int p = h & 1;
        u32x4 g = *(const u32x4*)((const char*)xs + swz3(h,w,dg<<4));
        #pragma unroll
        for(int q=0;q<4;q++){
          float a = ulo(g[q]), b = uhi(g[q]);
          m2[p][2*q]   = fminf(m2[p][2*q],   fmaxf(m1[p][2*q],   a)); m1[p][2*q]   = fminf(m1[p][2*q],   a);
          m2[p][2*q+1] = fminf(m2[p][2*q+1], fmaxf(m1[p][2*q+1], b)); m1[p][2*q+1] = fminf(m1[p][2*q+1], b);
        }
      }
      #pragma unroll
      for(int p=0;p<2;p++){
        u32 o[8];
        #pragma unroll
        for(int k=0;k<8;k++) o[k] = pack2(m1[p][k], m2[p][k]);
        int row = p*1024 + w*32;
        *(u32x4*)&th[row + (((2*dg  ) ^ (w&7))*4)] = (u32x4){o[0],o[1],o[2],o[3]};
        *(u32x4*)&th[row + (((2*dg+1) ^ (w&7))*4)] = (u32x4){o[4],o[5],o[6],o[7]};
      }
    }
  }
  __syncthreads();

  // P3: per D-line: combine meD (inline) + tabW + tabH, write xc
  short* __restrict__ px = xc + ((size_t)((bc>>7)*C2 + (bc&127)))*NVOX;
  short* __restrict__ pj = px + (size_t)CCH*NVOX;
  #pragma unroll
  for(int j=0;j<4;j++){
    int l = t + 256*j;
    int h = l>>5, w = l&31;
    u32x4 xr[4];
    #pragma unroll
    for(int g=0;g<4;g++)
      xr[g] = *(const u32x4*)((const char*)xs + swz3(h,w,g<<4));
    float xv[32];
    #pragma unroll
    for(int g=0;g<4;g++)
      #pragma unroll
      for(int q=0;q<4;q++){
        xv[g*8+2*q]   = ulo(xr[g][q]);
        xv[g*8+2*q+1] = uhi(xr[g][q]);
      }
    float m1d[2] = {1e30f,1e30f}, m2d[2] = {1e30f,1e30f};
    #pragma unroll
    for(int q=0;q<16;q++){
      m2d[0] = fminf(m2d[0], fmaxf(m1d[0], xv[2*q]));   m1d[0] = fminf(m1d[0], xv[2*q]);
      m2d[1] = fminf(m2d[1], fmaxf(m1d[1], xv[2*q+1])); m1d[1] = fminf(m1d[1], xv[2*q+1]);
    }
    const u32* twr = &tw[h*64 + (w&1)*32];
    int thbase = (h&1)*1024 + w*32, ws7 = w&7;
    u32 xjp[16];
    #pragma unroll
    for(int q=0;q<8;q++){
      u32x4 wv = *(const u32x4*)(twr + q*4);
      u32x4 hv = *(const u32x4*)(&th[thbase + ((q ^ ws7)*4)]);
      float o4[4];
      #pragma unroll
      for(int i=0;i<4;i++){
        int d = q*4 + i, p = d & 1;
        float xvv = xv[d];
        float meD = (xvv == m1d[p]) ? m2d[p] : m1d[p];
        float w1 = ulo(wv[i]);
        float meW = (xvv == w1) ? uhi(wv[i]) : w1;
        float h1 = ulo(hv[i]);
        float meH = (xvv == h1) ? uhi(hv[i]) : h1;
        float m = fminf(meD, fminf(meW, meH));
        o4[i] = fmaxf(0.0f, xvv - m);
      }
      xjp[q*2]   = pack2(o4[0], o4[1]);
      xjp[q*2+1] = pack2(o4[2], o4[3]);
    }
    #pragma unroll
    for(int g=0;g<4;g++){
      *(u32x4*)(px + (size_t)l*32 + g*8) = xr[g];
      *(u32x4*)(pj + (size_t)l*32 + g*8) = (u32x4){xjp[g*4],xjp[g*4+1],xjp[g*4+2],xjp[g*4+3]};
    }
  }
}

// ---- K2: y[b,o,v] = sum_c W[o,c]*xc[b,c,v], bf16 MFMA ------------------------
__global__ __launch_bounds__(256) void k_gemm(const short* __restrict__ xc, const short* __restrict__ wb,
                                              short* __restrict__ y){
  __shared__ __align__(16) char lds[32768];      // [v 128][c 128] bf16, swizzled blocks
  u32 blk = blockIdx.x;
  u32 vblk = blk & 255, b = blk >> 8;
  u32 vbase = vblk * 128;
  const short* __restrict__ xb = xc + (size_t)b*C2*NVOX + vbase;
  int t = threadIdx.x;
  int wave = t >> 6, lane = t & 63;
  int wr = wave >> 1, wc = wave & 1;    // o-half, v-half
  int l15 = lane & 15, l4 = lane >> 4;
  f32x4 acc[4][4];
  #pragma unroll
  for(int mt=0;mt<4;mt++)
    #pragma unroll
    for(int nt=0;nt<4;nt++) acc[mt][nt] = (f32x4){0.f,0.f,0.f,0.f};

  int v0  = (t & 15) * 8;     // 8 consecutive v this thread stages
  int cb2 = 2 * (t >> 4);     // even c base, +32*q

  #pragma unroll
  for(int kc=0;kc<2;kc++){
    s16x8 ra[4], rb[4];
    #pragma unroll
    for(int q=0;q<4;q++){
      const short* src = xb + (size_t)(kc*128 + cb2 + 32*q)*NVOX + v0;
      ra[q] = *(const s16x8*)(src);
      rb[q] = *(const s16x8*)(src + NVOX);
    }
    __syncthreads();
    #pragma unroll
    for(int q=0;q<4;q++){
      int c = cb2 + 32*q;
      #pragma unroll
      for(int e=0;e<8;e++){
        int v = v0 + e;
        u32 pr = ((u32)(u16)ra[q][e]) | (((u32)(u16)rb[q][e]) << 16);
        *(u32*)(lds + v*256 + ((((c>>3) ^ SWZ(v))<<4) | ((c&7)<<1))) = pr;
      }
    }
    __syncthreads();
    #pragma unroll
    for(int ks=0;ks<4;ks++){
      int kk = ks*32 + l4*8;
      s16x8 afrag[4], bfrag[4];
      #pragma unroll
      for(int nt=0;nt<4;nt++){
        int vloc = wc*64 + nt*16 + l15;
        bfrag[nt] = *(const s16x8*)(lds + vloc*256 + (((kk>>3) ^ SWZ(vloc))<<4));
      }
      #pragma unroll
      for(int mt=0;mt<4;mt++){
        int o = wr*64 + mt*16 + l15;
        afrag[mt] = *(const s16x8*)(wb + o*C2 + kc*128 + kk);
      }
      #pragma unroll
      for(int mt=0;mt<4;mt++)
        #pragma unroll
        for(int nt=0;nt<4;nt++)
          acc[mt][nt] = __builtin_amdgcn_mfma_f32_16x16x32_bf16(afrag[mt], bfrag[nt], acc[mt][nt], 0,0,0);
    }
  }

  __syncthreads();
  #pragma unroll
  for(int mt=0;mt<4;mt++){
    #pragma unroll
    for(int nt=0;nt<4;nt++){
      int vcol = wc*64 + nt*16 + l15;
      #pragma unroll
      for(int r=0;r<4;r++){
        int o = wr*64 + mt*16 + l4*4 + r;
        *(short*)(lds + o*256 + ((((vcol>>3) ^ SWZ(o))<<4) | ((vcol&7)<<1))) = f2bf(acc[mt][nt][r]);
      }
    }
  }
  __syncthreads();
  short* __restrict__ yb = y + (size_t)b*OO*NVOX + vbase;
  #pragma unroll
  for(int q=0;q<8;q++){
    int p = t + q*256;
    int o = p >> 4, vs = (p & 15) * 8;
    s16x8 val = *(const s16x8*)(lds + o*256 + ((((vs>>3) ^ SWZ(o))<<4)));
    *(s16x8*)(yb + (size_t)o*NVOX + vs) = val;
  }
}

// ---- K3a: per-(o,slice) partial sums ----------------------------------------
__global__ __launch_bounds__(256) void k_statsp(const short* __restrict__ y, float* __restrict__ part){
  int blk = blockIdx.x;       // o*8 + s
  int o = blk >> 3, s = blk & 7;
  int t = threadIdx.x;
  float sm = 0.f, ss = 0.f;
  for(int b=0;b<BB;b++){
    const short* p = y + ((size_t)b*OO + o)*NVOX + s*4096;
    #pragma unroll
    for(int it=0;it<2;it++){
      s16x8 u = *(const s16x8*)(p + (t + 256*it)*8);
      #pragma unroll
      for(int e=0;e<8;e++){ float f = bf2f(u[e]); sm += f; ss += f*f; }
    }
  }
  __shared__ float rs[256], rss[256];
  rs[t] = sm; rss[t] = ss;
  __syncthreads();
  for(int k=128;k>0;k>>=1){
    if(t<k){ rs[t]+=rs[t+k]; rss[t]+=rss[t+k]; }
    __syncthreads();
  }
  if(t==0){ part[2*blk] = rs[0]; part[2*blk+1] = rss[0]; }
}

// ---- K3b: finalize stats -----------------------------------------------------
__global__ __launch_bounds__(128) void k_statsf(const float* __restrict__ part, float* __restrict__ stats){
  int o = threadIdx.x;
  float sm = 0.f, ss = 0.f;
  #pragma unroll
  for(int s=0;s<8;s++){ sm += part[2*(o*8+s)]; ss += part[2*(o*8+s)+1]; }
  float inv = 1.0f/(float)NTOT;
  float mean = sm*inv;
  float var = ss*inv - mean*mean;
  stats[2*o]   = mean;
  stats[2*o+1] = rsqrtf(var + 1e-5f);
}

// ---- K4: BN scale-shift + exact-erf GELU ------------------------------------
__global__ __launch_bounds__(256) void k_bngelu(const short* __restrict__ y, const float* __restrict__ stats,
                                                const float* __restrict__ gamma, const float* __restrict__ beta,
                                                float* __restrict__ out){
  size_t base = ((size_t)blockIdx.x*256 + threadIdx.x)*8;
  int o = (int)((base >> 15) & 127);
  float mean = stats[2*o], rstd = stats[2*o+1];
  float g  = gamma[o]*rstd;
  float be = beta[o] - mean*g;
  s16x8 u = *(const s16x8*)(y + base);
  f32x4 r0, r1;
  #pragma unroll
  for(int e=0;e<8;e++){
    float yn = bf2f(u[e])*g + be;
    float ge = 0.5f*yn*(1.0f + erff(yn*0.70710678118654752f));
    if(e<4) r0[e] = ge; else r1[e-4] = ge;
  }
  *(f32x4*)(out + base)     = r0;
  *(f32x4*)(out + base + 4) = r1;
}

extern "C" void kernel_launch(void* const* d_in, const int* in_sizes, int n_in,
                              void* d_out, int out_size, void* d_ws, size_t ws_size,
                              hipStream_t stream) {
  (void)in_sizes; (void)n_in; (void)out_size; (void)ws_size;
  const float* x     = (const float*)d_in[0];
  const float* cw    = (const float*)d_in[1];
  // d_in[2] = conv_b: mathematically cancels in training-mode BatchNorm
  const float* gamma = (const float*)d_in[3];
  const float* beta  = (const float*)d_in[4];
  float* out = (float*)d_out;

  char* ws = (char*)d_ws;
  short* wb    = (short*)ws;                                   // 64 KB bf16 W
  short* y     = (short*)(ws + 65536);                         // 33.5 MB bf16 y
  float* stats = (float*)(ws + 65536 + (size_t)BB*OO*NVOX*2);  // 1 KB
  float* part  = stats + 256;                                  // 8 KB partials
  short* xcbuf = (short*)d_out;                                // xc lives in d_out

  k_convw <<<dim3((OO*C2)/256),     dim3(256), 0, stream>>>(cw, wb);
  k_xj    <<<dim3(BB*CCH),         dim3(256), 0, stream>>>(x, xcbuf);
  k_gemm  <<<dim3(BB*(NVOX/128)),  dim3(256), 0, stream>>>(xcbuf, wb, y);
  k_statsp<<<dim3(OO*8),           dim3(256), 0, stream>>>(y, part);
  k_statsf<<<dim3(1),              dim3(128), 0, stream>>>(part, stats);
  k_bngelu<<<dim3((NTOT*OO)/2048), dim3(256), 0, stream>>>(y, stats, gamma, beta, out);
}

// Round 4
// 98.797 us; speedup vs baseline: 1.6649x; 1.0165x over previous
//
#include <hip/hip_runtime.h>
#include <hip/hip_bf16.h>

#define BB 4
#define CCH 128
#define C2 256
#define OO 128
#define NVOX 32768            // 32*32*32 voxels per (b, channel)
#define NTOT (BB*NVOX)        // reduction count per output channel
#define NGB 1024              // gemm blocks (= stats partials)

typedef __attribute__((ext_vector_type(4))) float f32x4;
typedef __attribute__((ext_vector_type(8))) short s16x8;
typedef __attribute__((ext_vector_type(4))) unsigned int u32x4;
typedef __attribute__((ext_vector_type(2))) unsigned int u32x2;
typedef unsigned int u32;
typedef unsigned short u16;

// XOR swizzle on the 16B column-block index, keyed by row. Bijective per row. (GEMM)
#define SWZ(r) ((((r)>>3) ^ (r)) & 7)

__device__ __forceinline__ float bf2f(short s){
  union { u32 i; float f; } cv; cv.i = ((u32)(u16)s) << 16; return cv.f;
}
__device__ __forceinline__ short f2bf(float f){
  union { __hip_bfloat16 h; short s; } cv; cv.h = __float2bfloat16(f); return cv.s;
}
__device__ __forceinline__ u32 pack2(float a, float b){
  return ((u32)(u16)f2bf(a)) | (((u32)(u16)f2bf(b)) << 16);
}
__device__ __forceinline__ float ulo(u32 r){
  union { u32 i; float f; } cv; cv.i = r << 16; return cv.f;
}
__device__ __forceinline__ float uhi(u32 r){
  union { u32 i; float f; } cv; cv.i = r & 0xffff0000u; return cv.f;
}

// ---- K0: conv_w fp32 -> bf16 -------------------------------------------------
__global__ __launch_bounds__(256) void k_convw(const float* __restrict__ w, short* __restrict__ wb){
  int i = blockIdx.x*256 + threadIdx.x;
  wb[i] = f2bf(w[i]);
}

// ---- K1: x_j = max(0, x - min over same-parity-excl-self along H,W,D) -------
// One block per (b,c), 512 threads: whole 32^3 volume in LDS (bf16, swizzled).
// Per-axis min-excl-self via (min1,min2) parity-line tables:
// me = (x==min1)?min2:min1 (duplicate-inclusive min2 -> exact).
// LDS = 64KB volume + 8KB tabW + 8KB tabH = 80KB -> 2 blocks/CU, 16 waves/CU.

// byte offset of logical (h, w, byte-in-line) in swizzled volume
__device__ __forceinline__ int swz3(int h, int w, int bin){
  int s1 = ((w>>1) ^ h) & 3;           // permutes 16B granules inside the 64B line
  int s2 = ((w>>3) ^ (h>>2)) & 3;      // relocates lines among w&3 group
  return (h<<11) + ((w ^ s2)<<6) + ((bin & 15) | (((((bin>>4)) ^ s1) & 3) << 4));
}

__global__ __launch_bounds__(512, 4) void k_xj(const float* __restrict__ x, short* __restrict__ xc){
  __shared__ __align__(16) u32 xs[16384];   // 64KB: bf16 pairs, swizzled
  __shared__ __align__(16) u32 tw[2048];    // [h][pw][d] {min1,min2} packed
  __shared__ __align__(16) u32 th[2048];    // [ph][w][d], granule ^ (w&7)
  int t = threadIdx.x;
  u32 bc = blockIdx.x;
  const float* __restrict__ src = x + (size_t)bc*NVOX;

  // P1: stage volume as bf16, swizzled, coalesced f32x4 loads
  #pragma unroll
  for(int j=0;j<16;j++){
    int e0 = (t + 512*j)*4;
    f32x4 v = *(const f32x4*)(src + e0);
    int h = e0>>10, w = (e0>>5)&31, bin = (e0&31)*2;
    u32* dst = (u32*)((char*)xs + swz3(h,w,bin));
    dst[0] = pack2(v[0], v[1]);
    dst[1] = pack2(v[2], v[3]);
  }
  __syncthreads();

  // P2: 512 tasks. t<256: W-table (axis line h, 4-d quarter dq);
  //                t>=256: H-table (axis line w, dq). ds_read_b64 per step.
  {
    int dq = t & 7, aa = (t >> 3) & 31;
    float m1[2][4], m2[2][4];
    #pragma unroll
    for(int p=0;p<2;p++)
      #pragma unroll
      for(int k=0;k<4;k++){ m1[p][k]=1e30f; m2[p][k]=1e30f; }
    if(t < 256){
      int h = aa;
      #pragma unroll
      for(int w=0;w<32;w++){
        int p = w & 1;
        u32x2 g = *(const u32x2*)((const char*)xs + swz3(h,w,dq*8));
        #pragma unroll
        for(int q=0;q<2;q++){
          float a = ulo(g[q]), b = uhi(g[q]);
          m2[p][2*q]   = fminf(m2[p][2*q],   fmaxf(m1[p][2*q],   a)); m1[p][2*q]   = fminf(m1[p][2*q],   a);
          m2[p][2*q+1] = fminf(m2[p][2*q+1], fmaxf(m1[p][2*q+1], b)); m1[p][2*q+1] = fminf(m1[p][2*q+1], b);
        }
      }
      #pragma unroll
      for(int p=0;p<2;p++){
        u32 o0 = pack2(m1[p][0], m2[p][0]), o1 = pack2(m1[p][1], m2[p][1]);
        u32 o2 = pack2(m1[p][2], m2[p][2]), o3 = pack2(m1[p][3], m2[p][3]);
        *(u32x4*)&tw[h*64 + p*32 + dq*4] = (u32x4){o0,o1,o2,o3};
      }
    } else {
      int w = aa;
      #pragma unroll
      for(int h=0;h<32;h++){
        int p = h & 1;
        u32x2 g = *(const u32x2*)((const char*)xs + swz3(h,w,dq*8));
        #pragma unroll
        for(int q=0;q<2;q++){
          float a = ulo(g[q]), b = uhi(g[q]);
          m2[p][2*q]   = fminf(m2[p][2*q],   fmaxf(m1[p][2*q],   a)); m1[p][2*q]   = fminf(m1[p][2*q],   a);
          m2[p][2*q+1] = fminf(m2[p][2*q+1], fmaxf(m1[p][2*q+1], b)); m1[p][2*q+1] = fminf(m1[p][2*q+1], b);
        }
      }
      #pragma unroll
      for(int p=0;p<2;p++){
        u32 o0 = pack2(m1[p][0], m2[p][0]), o1 = pack2(m1[p][1], m2[p][1]);
        u32 o2 = pack2(m1[p][2], m2[p][2]), o3 = pack2(m1[p][3], m2[p][3]);
        *(u32x4*)&th[p*1024 + w*32 + ((dq ^ (w&7))*4)] = (u32x4){o0,o1,o2,o3};
      }
    }
  }
  __syncthreads();

  // P3: per D-line: combine meD (inline) + tabW + tabH, write xc
  short* __restrict__ px = xc + ((size_t)((bc>>7)*C2 + (bc&127)))*NVOX;
  short* __restrict__ pj = px + (size_t)CCH*NVOX;
  #pragma unroll
  for(int j=0;j<2;j++){
    int l = t + 512*j;
    int h = l>>5, w = l&31;
    u32x4 xr[4];
    #pragma unroll
    for(int g=0;g<4;g++)
      xr[g] = *(const u32x4*)((const char*)xs + swz3(h,w,g<<4));
    float xv[32];
    #pragma unroll
    for(int g=0;g<4;g++)
      #pragma unroll
      for(int q=0;q<4;q++){
        xv[g*8+2*q]   = ulo(xr[g][q]);
        xv[g*8+2*q+1] = uhi(xr[g][q]);
      }
    float m1d[2] = {1e30f,1e30f}, m2d[2] = {1e30f,1e30f};
    #pragma unroll
    for(int q=0;q<16;q++){
      m2d[0] = fminf(m2d[0], fmaxf(m1d[0], xv[2*q]));   m1d[0] = fminf(m1d[0], xv[2*q]);
      m2d[1] = fminf(m2d[1], fmaxf(m1d[1], xv[2*q+1])); m1d[1] = fminf(m1d[1], xv[2*q+1]);
    }
    const u32* twr = &tw[h*64 + (w&1)*32];
    int thbase = (h&1)*1024 + w*32, ws7 = w&7;
    u32 xjp[16];
    #pragma unroll
    for(int q=0;q<8;q++){
      u32x4 wv = *(const u32x4*)(twr + q*4);
      u32x4 hv = *(const u32x4*)(&th[thbase + ((q ^ ws7)*4)]);
      float o4[4];
      #pragma unroll
      for(int i=0;i<4;i++){
        int d = q*4 + i, p = d & 1;
        float xvv = xv[d];
        float meD = (xvv == m1d[p]) ? m2d[p] : m1d[p];
        float w1 = ulo(wv[i]);
        float meW = (xvv == w1) ? uhi(wv[i]) : w1;
        float h1 = ulo(hv[i]);
        float meH = (xvv == h1) ? uhi(hv[i]) : h1;
        float m = fminf(meD, fminf(meW, meH));
        o4[i] = fmaxf(0.0f, xvv - m);
      }
      xjp[q*2]   = pack2(o4[0], o4[1]);
      xjp[q*2+1] = pack2(o4[2], o4[3]);
    }
    #pragma unroll
    for(int g=0;g<4;g++){
      *(u32x4*)(px + (size_t)l*32 + g*8) = xr[g];
      *(u32x4*)(pj + (size_t)l*32 + g*8) = (u32x4){xjp[g*4],xjp[g*4+1],xjp[g*4+2],xjp[g*4+3]};
    }
  }
}

// ---- K2: y[b,o,v] = sum_c W[o,c]*xc[b,c,v], bf16 MFMA + fused BN partials ----
__global__ __launch_bounds__(256) void k_gemm(const short* __restrict__ xc, const short* __restrict__ wb,
                                              short* __restrict__ y, float* __restrict__ part){
  __shared__ __align__(16) char lds[32768];      // [v 128][c 128] bf16, swizzled blocks
  u32 blk = blockIdx.x;
  u32 vblk = blk & 255, b = blk >> 8;
  u32 vbase = vblk * 128;
  const short* __restrict__ xb = xc + (size_t)b*C2*NVOX + vbase;
  int t = threadIdx.x;
  int wave = t >> 6, lane = t & 63;
  int wr = wave >> 1, wc = wave & 1;    // o-half, v-half
  int l15 = lane & 15, l4 = lane >> 4;
  f32x4 acc[4][4];
  #pragma unroll
  for(int mt=0;mt<4;mt++)
    #pragma unroll
    for(int nt=0;nt<4;nt++) acc[mt][nt] = (f32x4){0.f,0.f,0.f,0.f};

  int v0  = (t & 15) * 8;     // 8 consecutive v this thread stages
  int cb2 = 2 * (t >> 4);     // even c base, +32*q

  #pragma unroll
  for(int kc=0;kc<2;kc++){
    s16x8 ra[4], rb[4];
    #pragma unroll
    for(int q=0;q<4;q++){
      const short* src = xb + (size_t)(kc*128 + cb2 + 32*q)*NVOX + v0;
      ra[q] = *(const s16x8*)(src);
      rb[q] = *(const s16x8*)(src + NVOX);
    }
    __syncthreads();
    #pragma unroll
    for(int q=0;q<4;q++){
      int c = cb2 + 32*q;
      #pragma unroll
      for(int e=0;e<8;e++){
        int v = v0 + e;
        u32 pr = ((u32)(u16)ra[q][e]) | (((u32)(u16)rb[q][e]) << 16);
        *(u32*)(lds + v*256 + ((((c>>3) ^ SWZ(v))<<4) | ((c&7)<<1))) = pr;
      }
    }
    __syncthreads();
    #pragma unroll
    for(int ks=0;ks<4;ks++){
      int kk = ks*32 + l4*8;
      s16x8 afrag[4], bfrag[4];
      #pragma unroll
      for(int nt=0;nt<4;nt++){
        int vloc = wc*64 + nt*16 + l15;
        bfrag[nt] = *(const s16x8*)(lds + vloc*256 + (((kk>>3) ^ SWZ(vloc))<<4));
      }
      #pragma unroll
      for(int mt=0;mt<4;mt++){
        int o = wr*64 + mt*16 + l15;
        afrag[mt] = *(const s16x8*)(wb + o*C2 + kc*128 + kk);
      }
      #pragma unroll
      for(int mt=0;mt<4;mt++)
        #pragma unroll
        for(int nt=0;nt<4;nt++)
          acc[mt][nt] = __builtin_amdgcn_mfma_f32_16x16x32_bf16(afrag[mt], bfrag[nt], acc[mt][nt], 0,0,0);
    }
  }

  // Epilogue: acc -> LDS [o 128][v 128] bf16 (swizzled) -> coalesced stores.
  // C/D: col = lane&15 (v), row = (lane>>4)*4 + r (o)   [m89-verified]
  __syncthreads();
  #pragma unroll
  for(int mt=0;mt<4;mt++){
    #pragma unroll
    for(int nt=0;nt<4;nt++){
      int vcol = wc*64 + nt*16 + l15;
      #pragma unroll
      for(int r=0;r<4;r++){
        int o = wr*64 + mt*16 + l4*4 + r;
        *(short*)(lds + o*256 + ((((vcol>>3) ^ SWZ(o))<<4) | ((vcol&7)<<1))) = f2bf(acc[mt][nt][r]);
      }
    }
  }
  __syncthreads();
  short* __restrict__ yb = y + (size_t)b*OO*NVOX + vbase;
  #pragma unroll
  for(int q=0;q<8;q++){
    int p = t + q*256;
    int o = p >> 4, vs = (p & 15) * 8;
    s16x8 val = *(const s16x8*)(lds + o*256 + ((((vs>>3) ^ SWZ(o))<<4)));
    *(s16x8*)(yb + (size_t)o*NVOX + vs) = val;
  }

  // Fused BN partial stats from the same LDS tile (values identical to y).
  {
    int o = t >> 1, vh = t & 1;
    float sm = 0.f, ss = 0.f;
    #pragma unroll
    for(int k=0;k<8;k++){
      int vs = vh*64 + k*8;
      s16x8 val = *(const s16x8*)(lds + o*256 + ((((vs>>3) ^ SWZ(o))<<4)));
      #pragma unroll
      for(int e=0;e<8;e++){ float f = bf2f(val[e]); sm += f; ss += f*f; }
    }
    sm += __shfl_xor(sm, 1);
    ss += __shfl_xor(ss, 1);
    if(vh == 0){
      float* pp = part + ((size_t)blk*OO + o)*2;
      pp[0] = sm; pp[1] = ss;
    }
  }
}

// ---- K3: finalize stats from 1024 per-block partials -------------------------
__global__ __launch_bounds__(256) void k_statsf(const float* __restrict__ part, float* __restrict__ stats){
  int o = blockIdx.x, t = threadIdx.x;
  float sm = 0.f, ss = 0.f;
  #pragma unroll
  for(int k=0;k<4;k++){
    int blk = t + k*256;
    const float* pp = part + ((size_t)blk*OO + o)*2;
    sm += pp[0]; ss += pp[1];
  }
  __shared__ float rs[256], rss[256];
  rs[t] = sm; rss[t] = ss;
  __syncthreads();
  for(int k=128;k>0;k>>=1){
    if(t<k){ rs[t]+=rs[t+k]; rss[t]+=rss[t+k]; }
    __syncthreads();
  }
  if(t==0){
    float inv = 1.0f/(float)NTOT;
    float mean = rs[0]*inv;
    float var = rss[0]*inv - mean*mean;
    stats[2*o]   = mean;
    stats[2*o+1] = rsqrtf(var + 1e-5f);
  }
}

// ---- K4: BN scale-shift + exact-erf GELU ------------------------------------
__global__ __launch_bounds__(256) void k_bngelu(const short* __restrict__ y, const float* __restrict__ stats,
                                                const float* __restrict__ gamma, const float* __restrict__ beta,
                                                float* __restrict__ out){
  size_t base = ((size_t)blockIdx.x*256 + threadIdx.x)*8;
  int o = (int)((base >> 15) & 127);
  float mean = stats[2*o], rstd = stats[2*o+1];
  float g  = gamma[o]*rstd;
  float be = beta[o] - mean*g;
  s16x8 u = *(const s16x8*)(y + base);
  f32x4 r0, r1;
  #pragma unroll
  for(int e=0;e<8;e++){
    float yn = bf2f(u[e])*g + be;
    float ge = 0.5f*yn*(1.0f + erff(yn*0.70710678118654752f));
    if(e<4) r0[e] = ge; else r1[e-4] = ge;
  }
  *(f32x4*)(out + base)     = r0;
  *(f32x4*)(out + base + 4) = r1;
}

extern "C" void kernel_launch(void* const* d_in, const int* in_sizes, int n_in,
                              void* d_out, int out_size, void* d_ws, size_t ws_size,
                              hipStream_t stream) {
  (void)in_sizes; (void)n_in; (void)out_size; (void)ws_size;
  const float* x     = (const float*)d_in[0];
  const float* cw    = (const float*)d_in[1];
  // d_in[2] = conv_b: mathematically cancels in training-mode BatchNorm
  const float* gamma = (const float*)d_in[3];
  const float* beta  = (const float*)d_in[4];
  float* out = (float*)d_out;

  char* ws = (char*)d_ws;
  short* wb    = (short*)ws;                                   // 64 KB bf16 W
  short* y     = (short*)(ws + 65536);                         // 33.5 MB bf16 y
  float* stats = (float*)(ws + 65536 + (size_t)BB*OO*NVOX*2);  // 1 KB
  float* part  = stats + 256;                                  // 1 MB partials
  short* xcbuf = (short*)d_out;                                // xc lives in d_out

  k_convw <<<dim3((OO*C2)/256),     dim3(256), 0, stream>>>(cw, wb);
  k_xj    <<<dim3(BB*CCH),         dim3(512), 0, stream>>>(x, xcbuf);
  k_gemm  <<<dim3(BB*(NVOX/128)),  dim3(256), 0, stream>>>(xcbuf, wb, y, part);
  k_statsf<<<dim3(OO),             dim3(256), 0, stream>>>(part, stats);
  k_bngelu<<<dim3((NTOT*OO)/2048), dim3(256), 0, stream>>>(y, stats, gamma, beta, out);
}